// Round 16
// baseline (194.727 us; speedup 1.0000x reference)
//
#include <hip/hip_runtime.h>

#define GROUPS 2
#define NUM_VARS 320
#define NVT 640
#define DIM 512
#define VAR_DIM 128
#define NTOK 48000
#define TM 32            // (fallback path) tokens per block
#define TMF 64           // fast-path tokens per block (4 row-tiles)
#define BLOCK 256
#define KCH 256          // (fallback path) K-chunk staged in LDS
#define XP 264           // (fallback path) padded row stride (ushorts)
#define NT16 40          // total 16-var tiles (NVT/16)
#define NKS 16           // total 32-k slices (DIM/32)
#define TSTRIDE (NKS * 2 * 512)   // u16 elements per packed W 16-row tile

typedef short bf16x8 __attribute__((ext_vector_type(8)));
typedef float f32x4  __attribute__((ext_vector_type(4)));
typedef unsigned short u16;
typedef u16 u16x4 __attribute__((ext_vector_type(4)));
typedef u16 u16x8 __attribute__((ext_vector_type(8)));

__device__ inline u16 bf16_rne(float f) {
    unsigned u = __builtin_bit_cast(unsigned, f);
    return (u16)((u + 0x7fffu + ((u >> 16) & 1u)) >> 16);
}
__device__ inline void split2(float f, u16& h, u16& l) {
    h = bf16_rne(f);
    float fh = __builtin_bit_cast(float, (unsigned)h << 16);
    l = bf16_rne(f - fh);
}
__device__ inline void split8(float4 a, float4 b, u16x8& hv, u16x8& lv) {
    u16 h, l;
    split2(a.x, h, l); hv[0] = h; lv[0] = l;
    split2(a.y, h, l); hv[1] = h; lv[1] = l;
    split2(a.z, h, l); hv[2] = h; lv[2] = l;
    split2(a.w, h, l); hv[3] = h; lv[3] = l;
    split2(b.x, h, l); hv[4] = h; lv[4] = l;
    split2(b.y, h, l); hv[5] = h; lv[5] = l;
    split2(b.z, h, l); hv[6] = h; lv[6] = l;
    split2(b.w, h, l); hv[7] = h; lv[7] = l;
}

// Pre-split W into bf16 hi/lo in MFMA-fragment order (validated R5-R15, absmax=0):
//   offset = ((v16*NKS+ks)*2+hilo)*512 + lane*8 + j
//   row = v16*16 + (lane&15), k = ks*32 + 8*(lane>>4) + j.
// R14 lesson: bf16x2 (dropping Blo) FAILS — true argmax can fall outside the
// computed top-2, which the f64 top-2 re-verify cannot catch. Keep bf16x3.
__global__ void pack_w_kernel(const float* __restrict__ W, u16* __restrict__ Wpk) {
    int idx = blockIdx.x * blockDim.x + threadIdx.x;
    if (idx >= NT16 * NKS * 64 * 8) return;
    int j    = idx & 7;
    int lane = (idx >> 3) & 63;
    int ks   = (idx >> 9) & 15;
    int v16  = idx >> 13;
    int row  = v16 * 16 + (lane & 15);
    int k    = ks * 32 + 8 * (lane >> 4) + j;
    u16 h, l;
    split2(W[(size_t)row * DIM + k], h, l);
    size_t base = (size_t)((v16 * NKS + ks) * 2) * 512 + lane * 8 + j;
    Wpk[base]       = h;
    Wpk[base + 512] = l;
}

// -------- fast path: fused x-split staging, 2 ks per barrier round ---------
// R15 accounting: per ks-round ~15000 SIMD-cyc vs 3500 of MFMA content; no BW
// is near a limit -> per-round latency convoy at the lockstep barrier (all
// waves drain, then simultaneously stall ~400cy on post-barrier B-loads).
// Convoy cost is per-ROUND, so process 2 ks per barrier: 8 rounds not 16.
// LDS 2 bufs x 4rt x (hi,lo) x 2ks x 1KB = 32KB. Numerics unchanged (bf16x3).
__global__ __launch_bounds__(BLOCK, 2)
void vq_mfma_fused_kernel(const float* __restrict__ x,
                          const float* __restrict__ W,
                          const u16* __restrict__ Wpk,
                          const float* __restrict__ bias,
                          const float* __restrict__ codebook,
                          float* __restrict__ out,
                          float* __restrict__ avg_out) {
    __shared__ u16 As[2][4][2][1024];    // [buf][rt][plane][ksp*512 + lane*8]
    __shared__ float avg_s[NUM_VARS];
    __shared__ float tv_s[TMF][4][2];
    __shared__ int   ti_s[TMF][4][2];
    __shared__ float m_s[TMF], gap_s[TMF], sum_s[TMF];
    __shared__ int   i1_s[TMF], i2_s[TMF], kb_s[TMF];

    const int tid  = threadIdx.x;
    const int lane = tid & 63;
    const int ty   = tid >> 6;
    const int l15  = lane & 15;
    const int l4   = lane >> 4;
    const int g    = blockIdx.x & 1;
    const int n0   = (blockIdx.x >> 1) * TMF;

    for (int i = tid; i < NUM_VARS; i += BLOCK) avg_s[i] = 0.f;

    const f32x4 zf = {0.f, 0.f, 0.f, 0.f};
    f32x4 acc[4][5];
#pragma unroll
    for (int rt = 0; rt < 4; ++rt)
#pragma unroll
        for (int ct = 0; ct < 5; ++ct) acc[rt][ct] = zf;

    // wave ty stages token-tile (n0/16 + ty); all waves consume all rt
    const float* xsrc = x + (size_t)(n0 + ty * 16 + l15) * DIM + 8 * l4;
    const u16* wpk_b = Wpk + (size_t)(g * 20 + ty * 5) * TSTRIDE + lane * 8;

    // prologue: stage ks=0,1 into buf0 slots 0,1
#pragma unroll
    for (int s = 0; s < 2; ++s) {
        float4 a = *(const float4*)(xsrc + s * 32);
        float4 b = *(const float4*)(xsrc + s * 32 + 4);
        u16x8 hv, lv;
        split8(a, b, hv, lv);
        *(u16x8*)&As[0][ty][0][s * 512 + lane * 8] = hv;
        *(u16x8*)&As[0][ty][1][s * 512 + lane * 8] = lv;
    }
    __syncthreads();

#pragma unroll 1
    for (int kp = 0; kp < NKS / 2; ++kp) {
        const int cur = kp & 1;
        // stage loads for pair kp+1 (issue early; named regs per rule #20)
        float4 sx0, sx1, sx2, sx3;
        if (kp < NKS / 2 - 1) {
            const float* xs2 = xsrc + (size_t)(2 * (kp + 1)) * 32;
            sx0 = *(const float4*)(xs2);
            sx1 = *(const float4*)(xs2 + 4);
            sx2 = *(const float4*)(xs2 + 32);
            sx3 = *(const float4*)(xs2 + 36);
        }
        // two ks segments, one barrier
#pragma unroll
        for (int ksp = 0; ksp < 2; ++ksp) {
            const int ks = 2 * kp + ksp;
            bf16x8 bh[5], bl[5];
#pragma unroll
            for (int ct = 0; ct < 5; ++ct) {
                const u16* wp = wpk_b + (size_t)(ct * NKS + ks) * 1024;
                bh[ct] = *(const bf16x8*)wp;
                bl[ct] = *(const bf16x8*)(wp + 512);
            }
#pragma unroll
            for (int rt = 0; rt < 4; ++rt) {
                bf16x8 ah = *(const bf16x8*)&As[cur][rt][0][ksp * 512 + lane * 8];
                bf16x8 al = *(const bf16x8*)&As[cur][rt][1][ksp * 512 + lane * 8];
#pragma unroll
                for (int ct = 0; ct < 5; ++ct) {
                    acc[rt][ct] = __builtin_amdgcn_mfma_f32_16x16x32_bf16(ah, bh[ct], acc[rt][ct], 0, 0, 0);
                    acc[rt][ct] = __builtin_amdgcn_mfma_f32_16x16x32_bf16(ah, bl[ct], acc[rt][ct], 0, 0, 0);
                    acc[rt][ct] = __builtin_amdgcn_mfma_f32_16x16x32_bf16(al, bh[ct], acc[rt][ct], 0, 0, 0);
                }
            }
        }
        // split + write buf (kp+1)&1 (last read at round kp-1; barrier-safe)
        if (kp < NKS / 2 - 1) {
            const int nb = (kp + 1) & 1;
            u16x8 hv, lv;
            split8(sx0, sx1, hv, lv);
            *(u16x8*)&As[nb][ty][0][lane * 8] = hv;
            *(u16x8*)&As[nb][ty][1][lane * 8] = lv;
            split8(sx2, sx3, hv, lv);
            *(u16x8*)&As[nb][ty][0][512 + lane * 8] = hv;
            *(u16x8*)&As[nb][ty][1][512 + lane * 8] = lv;
        }
        asm volatile("s_waitcnt lgkmcnt(0)" ::: "memory");
        __builtin_amdgcn_sched_barrier(0);
        __builtin_amdgcn_s_barrier();
    }

    // bias (zeros in harness; kept for generality)
#pragma unroll
    for (int ct = 0; ct < 5; ++ct) {
        float bv = bias[g * NUM_VARS + ty * 80 + ct * 16 + l15];
#pragma unroll
        for (int rt = 0; rt < 4; ++rt)
#pragma unroll
            for (int j = 0; j < 4; ++j) acc[rt][ct][j] += bv;
    }

    // per-token wave-local top-2 (16-lane butterfly)
#pragma unroll
    for (int rt = 0; rt < 4; ++rt)
#pragma unroll
    for (int j = 0; j < 4; ++j) {
        float v1 = -3.4e38f, v2 = -3.4e38f;
        int   i1 = 0x7fffffff, i2 = 0x7fffffff;
#pragma unroll
        for (int ct = 0; ct < 5; ++ct) {
            float val = acc[rt][ct][j];
            int   vi  = ty * 80 + ct * 16 + l15;
            if ((val > v1) || (val == v1 && vi < i1)) { v2 = v1; i2 = i1; v1 = val; i1 = vi; }
            else if ((val > v2) || (val == v2 && vi < i2)) { v2 = val; i2 = vi; }
        }
#pragma unroll
        for (int off = 1; off <= 8; off <<= 1) {
            float o1 = __shfl_xor(v1, off); int oi1 = __shfl_xor(i1, off);
            float o2 = __shfl_xor(v2, off); int oi2 = __shfl_xor(i2, off);
            if ((o1 > v1) || (o1 == v1 && oi1 < i1)) { v2 = v1; i2 = i1; v1 = o1; i1 = oi1; }
            else if ((o1 > v2) || (o1 == v2 && oi1 < i2)) { v2 = o1; i2 = oi1; }
            if ((o2 > v1) || (o2 == v1 && oi2 < i1)) { v2 = v1; i2 = i1; v1 = o2; i1 = oi2; }
            else if ((o2 > v2) || (o2 == v2 && oi2 < i2)) { v2 = o2; i2 = oi2; }
        }
        if (l15 == 0) {
            const int T = rt * 16 + l4 * 4 + j;
            tv_s[T][ty][0] = v1; tv_s[T][ty][1] = v2;
            ti_s[T][ty][0] = i1; ti_s[T][ty][1] = i2;
        }
    }
    __syncthreads();

    // cross-wave merge (one thread per token)
    if (tid < TMF) {
        float v1 = -3.4e38f, v2 = -3.4e38f;
        int   i1 = 0x7fffffff, i2 = 0x7fffffff;
#pragma unroll
        for (int w = 0; w < 4; ++w)
#pragma unroll
            for (int q = 0; q < 2; ++q) {
                float val = tv_s[tid][w][q]; int vi = ti_s[tid][w][q];
                if ((val > v1) || (val == v1 && vi < i1)) { v2 = v1; i2 = i1; v1 = val; i1 = vi; }
                else if ((val > v2) || (val == v2 && vi < i2)) { v2 = val; i2 = vi; }
            }
        m_s[tid] = v1; gap_s[tid] = v1 - v2;
        i1_s[tid] = i1; i2_s[tid] = i2; kb_s[tid] = i1; sum_s[tid] = 0.f;
    }
    __syncthreads();

    // softmax: exp + per-token sum
#pragma unroll
    for (int rt = 0; rt < 4; ++rt)
#pragma unroll
    for (int j = 0; j < 4; ++j) {
        const int T = rt * 16 + l4 * 4 + j;
        const float m = m_s[T];
        float s = 0.f;
#pragma unroll
        for (int ct = 0; ct < 5; ++ct) {
            float e = __expf(acc[rt][ct][j] - m);
            acc[rt][ct][j] = e;
            s += e;
        }
#pragma unroll
        for (int off = 1; off <= 8; off <<= 1) s += __shfl_xor(s, off);
        if (l15 == 0) atomicAdd(&sum_s[T], s);
    }
    __syncthreads();

    // avg_probs partials: hoisted reciprocal, l4-shuffle reduce,
    // per-wave-exclusive plain adds
#pragma unroll
    for (int ct = 0; ct < 5; ++ct) {
        float tot = 0.f;
#pragma unroll
        for (int rt = 0; rt < 4; ++rt)
#pragma unroll
        for (int j = 0; j < 4; ++j) {
            const int T = rt * 16 + l4 * 4 + j;
            float v = acc[rt][ct][j] * (1.f / sum_s[T]);
            v += __shfl_xor(v, 16);
            v += __shfl_xor(v, 32);
            tot += v;
        }
        if (l4 == 0) avg_s[ty * 80 + ct * 16 + l15] += tot;
    }

    // f64 re-verify close argmaxes (bf16x3 logit err ~3e-4 << 0.05 gap)
    for (int t16 = 0; t16 < 16; ++t16) {
        const int T = ty * 16 + t16;
        if (gap_s[T] <= 0.05f) {
            const int i1 = i1_s[T], i2 = i2_s[T];
            const float* xr = x + (size_t)(n0 + T) * DIM;
            const float* w1 = W + (size_t)(g * NUM_VARS + i1) * DIM;
            const float* w2 = W + (size_t)(g * NUM_VARS + i2) * DIM;
            double d1 = 0.0, d2 = 0.0;
            for (int k = lane; k < DIM; k += 64) {
                double xv = (double)xr[k];
                d1 += xv * (double)w1[k];
                d2 += xv * (double)w2[k];
            }
#pragma unroll
            for (int off = 1; off <= 32; off <<= 1) {
                d1 += __shfl_xor(d1, off);
                d2 += __shfl_xor(d2, off);
            }
            d1 += (double)bias[g * NUM_VARS + i1];
            d2 += (double)bias[g * NUM_VARS + i2];
            if (lane == 0)
                kb_s[T] = (d2 > d1 || (d2 == d1 && i2 < i1)) ? i2 : i1;
        }
    }
    __syncthreads();

    // codebook gather -> out (coalesced float4): 64 tokens x 32 float4
#pragma unroll
    for (int i = 0; i < 8; ++i) {
        const int f = tid + i * BLOCK;
        const int T = f >> 5, p = f & 31;
        const int kb = kb_s[T];
        float4 cv = *(const float4*)(codebook +
                     (size_t)(g * NUM_VARS + kb) * VAR_DIM + p * 4);
        *(float4*)(out + (size_t)(n0 + T) * (GROUPS * VAR_DIM) + g * VAR_DIM + p * 4) = cv;
    }

    const float scale = 1.f / (float)NTOK;
    for (int i = tid; i < NUM_VARS; i += BLOCK)
        atomicAdd(&avg_out[g * NUM_VARS + i], avg_s[i] * scale);
}

// ---------------- fallback path (no workspace): in-loop W split ------------
__global__ __launch_bounds__(BLOCK, 2)
void vq_mfma_kernel(const float* __restrict__ x,
                    const float* __restrict__ W,
                    const float* __restrict__ bias,
                    const float* __restrict__ codebook,
                    float* __restrict__ out,
                    float* __restrict__ avg_out) {
    __shared__ u16 xs_hi[TM][XP];
    __shared__ u16 xs_lo[TM][XP];
    __shared__ float avg_s[NUM_VARS];
    __shared__ float tv_s[TM][4][2];
    __shared__ int   ti_s[TM][4][2];
    __shared__ float m_s[TM], gap_s[TM], sum_s[TM];
    __shared__ int   i1_s[TM], i2_s[TM], kb_s[TM];

    const int tid  = threadIdx.x;
    const int lane = tid & 63;
    const int ty   = tid >> 6;
    const int l15  = lane & 15;
    const int l4   = lane >> 4;
    const int g    = blockIdx.x & 1;
    const int n0   = (blockIdx.x >> 1) * TM;

    for (int i = tid; i < NUM_VARS; i += BLOCK) avg_s[i] = 0.f;

    const f32x4 zf = {0.f, 0.f, 0.f, 0.f};
    f32x4 acc[2][5];
#pragma unroll
    for (int rt = 0; rt < 2; ++rt)
#pragma unroll
        for (int ct = 0; ct < 5; ++ct) acc[rt][ct] = zf;

    const int vw = g * NUM_VARS + ty * 80;

    for (int c = 0; c < DIM / KCH; ++c) {
        __syncthreads();
        {
            const int t  = tid >> 3;
            const int kb = (tid & 7) * 4;
            const float* xp = x + (size_t)(n0 + t) * DIM + c * KCH;
#pragma unroll
            for (int i = 0; i < 8; ++i) {
                const int k = kb + i * 32;
                float4 v = *(const float4*)(xp + k);
                u16x4 hv, lv; u16 h, l;
                split2(v.x, h, l); hv[0] = h; lv[0] = l;
                split2(v.y, h, l); hv[1] = h; lv[1] = l;
                split2(v.z, h, l); hv[2] = h; lv[2] = l;
                split2(v.w, h, l); hv[3] = h; lv[3] = l;
                *(u16x4*)&xs_hi[t][k] = hv;
                *(u16x4*)&xs_lo[t][k] = lv;
            }
        }
        __syncthreads();
#pragma unroll
        for (int ks = 0; ks < KCH / 32; ++ks) {
            const int ko = ks * 32 + 8 * l4;
            bf16x8 ah0 = *(const bf16x8*)&xs_hi[l15][ko];
            bf16x8 al0 = *(const bf16x8*)&xs_lo[l15][ko];
            bf16x8 ah1 = *(const bf16x8*)&xs_hi[16 + l15][ko];
            bf16x8 al1 = *(const bf16x8*)&xs_lo[16 + l15][ko];
            const int kg = c * KCH + ks * 32 + 8 * l4;
#pragma unroll
            for (int ct = 0; ct < 5; ++ct) {
                const float* wp = W + (size_t)(vw + ct * 16 + l15) * DIM + kg;
                float4 wa = *(const float4*)wp;
                float4 wb = *(const float4*)(wp + 4);
                bf16x8 bh, bl; u16 h, l;
                split2(wa.x, h, l); bh[0] = (short)h; bl[0] = (short)l;
                split2(wa.y, h, l); bh[1] = (short)h; bl[1] = (short)l;
                split2(wa.z, h, l); bh[2] = (short)h; bl[2] = (short)l;
                split2(wa.w, h, l); bh[3] = (short)h; bl[3] = (short)l;
                split2(wb.x, h, l); bh[4] = (short)h; bl[4] = (short)l;
                split2(wb.y, h, l); bh[5] = (short)h; bl[5] = (short)l;
                split2(wb.z, h, l); bh[6] = (short)h; bl[6] = (short)l;
                split2(wb.w, h, l); bh[7] = (short)h; bl[7] = (short)l;
                acc[0][ct] = __builtin_amdgcn_mfma_f32_16x16x32_bf16(ah0, bh, acc[0][ct], 0, 0, 0);
                acc[0][ct] = __builtin_amdgcn_mfma_f32_16x16x32_bf16(ah0, bl, acc[0][ct], 0, 0, 0);
                acc[0][ct] = __builtin_amdgcn_mfma_f32_16x16x32_bf16(al0, bh, acc[0][ct], 0, 0, 0);
                acc[1][ct] = __builtin_amdgcn_mfma_f32_16x16x32_bf16(ah1, bh, acc[1][ct], 0, 0, 0);
                acc[1][ct] = __builtin_amdgcn_mfma_f32_16x16x32_bf16(ah1, bl, acc[1][ct], 0, 0, 0);
                acc[1][ct] = __builtin_amdgcn_mfma_f32_16x16x32_bf16(al1, bh, acc[1][ct], 0, 0, 0);
            }
        }
    }

#pragma unroll
    for (int ct = 0; ct < 5; ++ct) {
        float bv = bias[vw + ct * 16 + l15];
#pragma unroll
        for (int rt = 0; rt < 2; ++rt)
#pragma unroll
            for (int j = 0; j < 4; ++j) acc[rt][ct][j] += bv;
    }

#pragma unroll
    for (int rt = 0; rt < 2; ++rt)
#pragma unroll
    for (int j = 0; j < 4; ++j) {
        float v1 = -3.4e38f, v2 = -3.4e38f;
        int   i1 = 0x7fffffff, i2 = 0x7fffffff;
#pragma unroll
        for (int ct = 0; ct < 5; ++ct) {
            float val = acc[rt][ct][j];
            int   vi  = ty * 80 + ct * 16 + l15;
            if ((val > v1) || (val == v1 && vi < i1)) { v2 = v1; i2 = i1; v1 = val; i1 = vi; }
            else if ((val > v2) || (val == v2 && vi < i2)) { v2 = val; i2 = vi; }
        }
#pragma unroll
        for (int off = 1; off <= 8; off <<= 1) {
            float o1 = __shfl_xor(v1, off); int oi1 = __shfl_xor(i1, off);
            float o2 = __shfl_xor(v2, off); int oi2 = __shfl_xor(i2, off);
            if ((o1 > v1) || (o1 == v1 && oi1 < i1)) { v2 = v1; i2 = i1; v1 = o1; i1 = oi1; }
            else if ((o1 > v2) || (o1 == v2 && oi1 < i2)) { v2 = o1; i2 = oi1; }
            if ((o2 > v1) || (o2 == v1 && oi2 < i1)) { v2 = v1; i2 = i1; v1 = o2; i1 = oi2; }
            else if ((o2 > v2) || (o2 == v2 && oi2 < i2)) { v2 = o2; i2 = oi2; }
        }
        if (l15 == 0) {
            const int T = rt * 16 + l4 * 4 + j;
            tv_s[T][ty][0] = v1; tv_s[T][ty][1] = v2;
            ti_s[T][ty][0] = i1; ti_s[T][ty][1] = i2;
        }
    }
    __syncthreads();

    if (tid < TM) {
        float v1 = -3.4e38f, v2 = -3.4e38f;
        int   i1 = 0x7fffffff, i2 = 0x7fffffff;
#pragma unroll
        for (int w = 0; w < 4; ++w)
#pragma unroll
            for (int q = 0; q < 2; ++q) {
                float val = tv_s[tid][w][q]; int vi = ti_s[tid][w][q];
                if ((val > v1) || (val == v1 && vi < i1)) { v2 = v1; i2 = i1; v1 = val; i1 = vi; }
                else if ((val > v2) || (val == v2 && vi < i2)) { v2 = val; i2 = vi; }
            }
        m_s[tid] = v1; gap_s[tid] = v1 - v2;
        i1_s[tid] = i1; i2_s[tid] = i2; kb_s[tid] = i1; sum_s[tid] = 0.f;
    }
    __syncthreads();

#pragma unroll
    for (int rt = 0; rt < 2; ++rt)
#pragma unroll
    for (int j = 0; j < 4; ++j) {
        const int T = rt * 16 + l4 * 4 + j;
        const float m = m_s[T];
        float s = 0.f;
#pragma unroll
        for (int ct = 0; ct < 5; ++ct) {
            float e = expf(acc[rt][ct][j] - m);
            acc[rt][ct][j] = e;
            s += e;
        }
#pragma unroll
        for (int off = 1; off <= 8; off <<= 1) s += __shfl_xor(s, off);
        if (l15 == 0) atomicAdd(&sum_s[T], s);
    }
    __syncthreads();

#pragma unroll
    for (int ct = 0; ct < 5; ++ct) {
        float tot = 0.f;
#pragma unroll
        for (int rt = 0; rt < 2; ++rt)
#pragma unroll
        for (int j = 0; j < 4; ++j) {
            const int T = rt * 16 + l4 * 4 + j;
            float v = acc[rt][ct][j] / sum_s[T];
            v += __shfl_xor(v, 16);
            v += __shfl_xor(v, 32);
            tot += v;
        }
        if (l4 == 0) avg_s[ty * 80 + ct * 16 + l15] += tot;
    }

    for (int t8 = 0; t8 < 8; ++t8) {
        const int T = ty * 8 + t8;
        if (gap_s[T] <= 0.05f) {
            const int i1 = i1_s[T], i2 = i2_s[T];
            const float* xr = x + (size_t)(n0 + T) * DIM;
            const float* w1 = W + (size_t)(g * NUM_VARS + i1) * DIM;
            const float* w2 = W + (size_t)(g * NUM_VARS + i2) * DIM;
            double d1 = 0.0, d2 = 0.0;
            for (int k = lane; k < DIM; k += 64) {
                double xv = (double)xr[k];
                d1 += xv * (double)w1[k];
                d2 += xv * (double)w2[k];
            }
#pragma unroll
            for (int off = 1; off <= 32; off <<= 1) {
                d1 += __shfl_xor(d1, off);
                d2 += __shfl_xor(d2, off);
            }
            d1 += (double)bias[g * NUM_VARS + i1];
            d2 += (double)bias[g * NUM_VARS + i2];
            if (lane == 0)
                kb_s[T] = (d2 > d1 || (d2 == d1 && i2 < i1)) ? i2 : i1;
        }
    }
    __syncthreads();

#pragma unroll
    for (int i = 0; i < 4; ++i) {
        const int f = tid + i * BLOCK;
        const int T = f >> 5, p = f & 31;
        const int kb = kb_s[T];
        float4 cv = *(const float4*)(codebook +
                     (size_t)(g * NUM_VARS + kb) * VAR_DIM + p * 4);
        *(float4*)(out + (size_t)(n0 + T) * (GROUPS * VAR_DIM) + g * VAR_DIM + p * 4) = cv;
    }

    const float scale = 1.f / (float)NTOK;
    for (int i = tid; i < NUM_VARS; i += BLOCK)
        atomicAdd(&avg_out[g * NUM_VARS + i], avg_s[i] * scale);
}

extern "C" void kernel_launch(void* const* d_in, const int* in_sizes, int n_in,
                              void* d_out, int out_size, void* d_ws, size_t ws_size,
                              hipStream_t stream) {
    const float* x  = (const float*)d_in[0];
    const float* W  = (const float*)d_in[1];
    const float* b  = (const float*)d_in[2];
    const float* cb = (const float*)d_in[3];
    float* out = (float*)d_out;
    float* avg = out + (size_t)NTOK * GROUPS * VAR_DIM;

    hipMemsetAsync(avg, 0, NVT * sizeof(float), stream);

    const size_t wpk_bytes = (size_t)NT16 * NKS * 2 * 512 * sizeof(u16);   // 1.31 MB

    if (ws_size >= wpk_bytes) {
        u16* Wpk = (u16*)d_ws;
        pack_w_kernel<<<(NT16 * NKS * 64 * 8 + 255) / 256, 256, 0, stream>>>(W, Wpk);
        vq_mfma_fused_kernel<<<(NTOK / TMF) * GROUPS, BLOCK, 0, stream>>>(
            x, W, Wpk, b, cb, out, avg);
    } else {
        vq_mfma_kernel<<<(NTOK / TM) * GROUPS, BLOCK, 0, stream>>>(x, W, b, cb, out, avg);
    }
}

// Round 17
// 162.824 us; speedup vs baseline: 1.1959x; 1.1959x over previous
//
#include <hip/hip_runtime.h>

#define GROUPS 2
#define NUM_VARS 320
#define NVT 640
#define DIM 512
#define VAR_DIM 128
#define NTOK 48000
#define TM 32            // (fallback path) tokens per block
#define TMF 64           // fast-path tokens per block (4 row-tiles)
#define BLOCK 256
#define KCH 256          // (fallback path) K-chunk staged in LDS
#define XP 264           // (fallback path) padded row stride (ushorts)
#define NT16 40          // total 16-var tiles (NVT/16)
#define NKS 16           // total 32-k slices (DIM/32)
#define TSTRIDE (NKS * 2 * 512)   // u16 elements per packed W 16-row tile

typedef short bf16x8 __attribute__((ext_vector_type(8)));
typedef float f32x4  __attribute__((ext_vector_type(4)));
typedef unsigned short u16;
typedef u16 u16x4 __attribute__((ext_vector_type(4)));
typedef u16 u16x8 __attribute__((ext_vector_type(8)));

__device__ inline u16 bf16_rne(float f) {
    unsigned u = __builtin_bit_cast(unsigned, f);
    return (u16)((u + 0x7fffu + ((u >> 16) & 1u)) >> 16);
}
__device__ inline void split2(float f, u16& h, u16& l) {
    h = bf16_rne(f);
    float fh = __builtin_bit_cast(float, (unsigned)h << 16);
    l = bf16_rne(f - fh);
}
__device__ inline void split8(float4 a, float4 b, u16x8& hv, u16x8& lv) {
    u16 h, l;
    split2(a.x, h, l); hv[0] = h; lv[0] = l;
    split2(a.y, h, l); hv[1] = h; lv[1] = l;
    split2(a.z, h, l); hv[2] = h; lv[2] = l;
    split2(a.w, h, l); hv[3] = h; lv[3] = l;
    split2(b.x, h, l); hv[4] = h; lv[4] = l;
    split2(b.y, h, l); hv[5] = h; lv[5] = l;
    split2(b.z, h, l); hv[6] = h; lv[6] = l;
    split2(b.w, h, l); hv[7] = h; lv[7] = l;
}

// Pre-split W into bf16 hi/lo in MFMA-fragment order (validated R5-R15, absmax=0):
//   offset = ((v16*NKS+ks)*2+hilo)*512 + lane*8 + j
//   row = v16*16 + (lane&15), k = ks*32 + 8*(lane>>4) + j.
// R14 lesson: bf16x2 (dropping Blo) FAILS — the true argmax can fall outside
// the computed top-2, which the f64 top-2 re-verify cannot catch. Keep bf16x3.
// R16 lesson: 2-ks-per-barrier regressed (VGPR 76->96, occ 30->21%) — the
// round cost is B-segment L2 latency hidden by wave overlap, not a
// per-barrier convoy; do not trade occupancy for fewer barriers.
__global__ void pack_w_kernel(const float* __restrict__ W, u16* __restrict__ Wpk) {
    int idx = blockIdx.x * blockDim.x + threadIdx.x;
    if (idx >= NT16 * NKS * 64 * 8) return;
    int j    = idx & 7;
    int lane = (idx >> 3) & 63;
    int ks   = (idx >> 9) & 15;
    int v16  = idx >> 13;
    int row  = v16 * 16 + (lane & 15);
    int k    = ks * 32 + 8 * (lane >> 4) + j;
    u16 h, l;
    split2(W[(size_t)row * DIM + k], h, l);
    size_t base = (size_t)((v16 * NKS + ks) * 2) * 512 + lane * 8 + j;
    Wpk[base]       = h;
    Wpk[base + 512] = l;
}

// -------- fast path: fused x-split staging (no pre-pass), TMF=64, bf16x3 ----
// Best verified configuration (R15: 162.7us total, absmax 0). Wave ty
// reg-stages its token-tile (T14 issue-early / split+ds_write-late), 3-buffer
// rotation, lgkmcnt(0)+sched_barrier+s_barrier per ks. B (hi+lo) direct from
// L2-resident Wpk. acc = 80 f32; 76 VGPR -> 3 waves/SIMD.
__global__ __launch_bounds__(BLOCK, 2)
void vq_mfma_fused_kernel(const float* __restrict__ x,
                          const float* __restrict__ W,
                          const u16* __restrict__ Wpk,
                          const float* __restrict__ bias,
                          const float* __restrict__ codebook,
                          float* __restrict__ out,
                          float* __restrict__ avg_out) {
    __shared__ u16 As[3][4][2][512];     // 3 bufs x 4 rt x (hi,lo) x 1KB = 24KB
    __shared__ float avg_s[NUM_VARS];
    __shared__ float tv_s[TMF][4][2];
    __shared__ int   ti_s[TMF][4][2];
    __shared__ float m_s[TMF], gap_s[TMF], sum_s[TMF];
    __shared__ int   i1_s[TMF], i2_s[TMF], kb_s[TMF];

    const int tid  = threadIdx.x;
    const int lane = tid & 63;
    const int ty   = tid >> 6;
    const int l15  = lane & 15;
    const int l4   = lane >> 4;
    const int g    = blockIdx.x & 1;
    const int n0   = (blockIdx.x >> 1) * TMF;

    for (int i = tid; i < NUM_VARS; i += BLOCK) avg_s[i] = 0.f;

    const f32x4 zf = {0.f, 0.f, 0.f, 0.f};
    f32x4 acc[4][5];
#pragma unroll
    for (int rt = 0; rt < 4; ++rt)
#pragma unroll
        for (int ct = 0; ct < 5; ++ct) acc[rt][ct] = zf;

    // wave ty stages token-tile (n0/16 + ty); all waves consume all rt
    const float* xsrc = x + (size_t)(n0 + ty * 16 + l15) * DIM + 8 * l4;
    const u16* wpk_b = Wpk + (size_t)(g * 20 + ty * 5) * TSTRIDE + lane * 8;

    // prologue: stage ks=0,1 serially into buf 0,1
#pragma unroll
    for (int s = 0; s < 2; ++s) {
        float4 a = *(const float4*)(xsrc + s * 32);
        float4 b = *(const float4*)(xsrc + s * 32 + 4);
        u16x8 hv, lv;
        split8(a, b, hv, lv);
        *(u16x8*)&As[s][ty][0][lane * 8] = hv;
        *(u16x8*)&As[s][ty][1][lane * 8] = lv;
    }
    __syncthreads();

#pragma unroll 1
    for (int ks = 0; ks < NKS; ++ks) {
        const int cur = ks % 3;
        // B fragments (L2-resident Wpk) — issued first (oldest in VMEM queue)
        bf16x8 bh[5], bl[5];
#pragma unroll
        for (int ct = 0; ct < 5; ++ct) {
            const u16* wp = wpk_b + (size_t)(ct * NKS + ks) * 1024;
            bh[ct] = *(const bf16x8*)wp;
            bl[ct] = *(const bf16x8*)(wp + 512);
        }
        // stage loads for ks+2 (newest — not forced by B waits)
        float4 sx0, sx1;
        const int kst = ks + 2;
        if (kst < NKS) {
            sx0 = *(const float4*)(xsrc + (size_t)kst * 32);
            sx1 = *(const float4*)(xsrc + (size_t)kst * 32 + 4);
        }
        // A from LDS, 15 MFMAs per rt
#pragma unroll
        for (int rt = 0; rt < 4; ++rt) {
            bf16x8 ah = *(const bf16x8*)&As[cur][rt][0][lane * 8];
            bf16x8 al = *(const bf16x8*)&As[cur][rt][1][lane * 8];
#pragma unroll
            for (int ct = 0; ct < 5; ++ct) {
                acc[rt][ct] = __builtin_amdgcn_mfma_f32_16x16x32_bf16(ah, bh[ct], acc[rt][ct], 0, 0, 0);
                acc[rt][ct] = __builtin_amdgcn_mfma_f32_16x16x32_bf16(ah, bl[ct], acc[rt][ct], 0, 0, 0);
                acc[rt][ct] = __builtin_amdgcn_mfma_f32_16x16x32_bf16(al, bh[ct], acc[rt][ct], 0, 0, 0);
            }
        }
        // split + write buf (ks+2)%3 (read at iter ks-1; barrier-safe)
        if (kst < NKS) {
            const int nb = kst % 3;
            u16x8 hv, lv;
            split8(sx0, sx1, hv, lv);
            *(u16x8*)&As[nb][ty][0][lane * 8] = hv;
            *(u16x8*)&As[nb][ty][1][lane * 8] = lv;
        }
        asm volatile("s_waitcnt lgkmcnt(0)" ::: "memory");
        __builtin_amdgcn_sched_barrier(0);
        __builtin_amdgcn_s_barrier();
    }

    // bias (zeros in harness; kept for generality)
#pragma unroll
    for (int ct = 0; ct < 5; ++ct) {
        float bv = bias[g * NUM_VARS + ty * 80 + ct * 16 + l15];
#pragma unroll
        for (int rt = 0; rt < 4; ++rt)
#pragma unroll
            for (int j = 0; j < 4; ++j) acc[rt][ct][j] += bv;
    }

    // per-token wave-local top-2 (16-lane butterfly)
#pragma unroll
    for (int rt = 0; rt < 4; ++rt)
#pragma unroll
    for (int j = 0; j < 4; ++j) {
        float v1 = -3.4e38f, v2 = -3.4e38f;
        int   i1 = 0x7fffffff, i2 = 0x7fffffff;
#pragma unroll
        for (int ct = 0; ct < 5; ++ct) {
            float val = acc[rt][ct][j];
            int   vi  = ty * 80 + ct * 16 + l15;
            if ((val > v1) || (val == v1 && vi < i1)) { v2 = v1; i2 = i1; v1 = val; i1 = vi; }
            else if ((val > v2) || (val == v2 && vi < i2)) { v2 = val; i2 = vi; }
        }
#pragma unroll
        for (int off = 1; off <= 8; off <<= 1) {
            float o1 = __shfl_xor(v1, off); int oi1 = __shfl_xor(i1, off);
            float o2 = __shfl_xor(v2, off); int oi2 = __shfl_xor(i2, off);
            if ((o1 > v1) || (o1 == v1 && oi1 < i1)) { v2 = v1; i2 = i1; v1 = o1; i1 = oi1; }
            else if ((o1 > v2) || (o1 == v2 && oi1 < i2)) { v2 = o1; i2 = oi1; }
            if ((o2 > v1) || (o2 == v1 && oi2 < i1)) { v2 = v1; i2 = i1; v1 = o2; i1 = oi2; }
            else if ((o2 > v2) || (o2 == v2 && oi2 < i2)) { v2 = o2; i2 = oi2; }
        }
        if (l15 == 0) {
            const int T = rt * 16 + l4 * 4 + j;
            tv_s[T][ty][0] = v1; tv_s[T][ty][1] = v2;
            ti_s[T][ty][0] = i1; ti_s[T][ty][1] = i2;
        }
    }
    __syncthreads();

    // cross-wave merge (one thread per token)
    if (tid < TMF) {
        float v1 = -3.4e38f, v2 = -3.4e38f;
        int   i1 = 0x7fffffff, i2 = 0x7fffffff;
#pragma unroll
        for (int w = 0; w < 4; ++w)
#pragma unroll
            for (int q = 0; q < 2; ++q) {
                float val = tv_s[tid][w][q]; int vi = ti_s[tid][w][q];
                if ((val > v1) || (val == v1 && vi < i1)) { v2 = v1; i2 = i1; v1 = val; i1 = vi; }
                else if ((val > v2) || (val == v2 && vi < i2)) { v2 = val; i2 = vi; }
            }
        m_s[tid] = v1; gap_s[tid] = v1 - v2;
        i1_s[tid] = i1; i2_s[tid] = i2; kb_s[tid] = i1; sum_s[tid] = 0.f;
    }
    __syncthreads();

    // softmax: exp + per-token sum
#pragma unroll
    for (int rt = 0; rt < 4; ++rt)
#pragma unroll
    for (int j = 0; j < 4; ++j) {
        const int T = rt * 16 + l4 * 4 + j;
        const float m = m_s[T];
        float s = 0.f;
#pragma unroll
        for (int ct = 0; ct < 5; ++ct) {
            float e = __expf(acc[rt][ct][j] - m);
            acc[rt][ct][j] = e;
            s += e;
        }
#pragma unroll
        for (int off = 1; off <= 8; off <<= 1) s += __shfl_xor(s, off);
        if (l15 == 0) atomicAdd(&sum_s[T], s);
    }
    __syncthreads();

    // avg_probs partials: hoisted reciprocal, l4-shuffle reduce,
    // per-wave-exclusive plain adds
#pragma unroll
    for (int ct = 0; ct < 5; ++ct) {
        float tot = 0.f;
#pragma unroll
        for (int rt = 0; rt < 4; ++rt)
#pragma unroll
        for (int j = 0; j < 4; ++j) {
            const int T = rt * 16 + l4 * 4 + j;
            float v = acc[rt][ct][j] * (1.f / sum_s[T]);
            v += __shfl_xor(v, 16);
            v += __shfl_xor(v, 32);
            tot += v;
        }
        if (l4 == 0) avg_s[ty * 80 + ct * 16 + l15] += tot;
    }

    // f64 re-verify close argmaxes (bf16x3 logit err ~3e-4 << 0.05 gap)
    for (int t16 = 0; t16 < 16; ++t16) {
        const int T = ty * 16 + t16;
        if (gap_s[T] <= 0.05f) {
            const int i1 = i1_s[T], i2 = i2_s[T];
            const float* xr = x + (size_t)(n0 + T) * DIM;
            const float* w1 = W + (size_t)(g * NUM_VARS + i1) * DIM;
            const float* w2 = W + (size_t)(g * NUM_VARS + i2) * DIM;
            double d1 = 0.0, d2 = 0.0;
            for (int k = lane; k < DIM; k += 64) {
                double xv = (double)xr[k];
                d1 += xv * (double)w1[k];
                d2 += xv * (double)w2[k];
            }
#pragma unroll
            for (int off = 1; off <= 32; off <<= 1) {
                d1 += __shfl_xor(d1, off);
                d2 += __shfl_xor(d2, off);
            }
            d1 += (double)bias[g * NUM_VARS + i1];
            d2 += (double)bias[g * NUM_VARS + i2];
            if (lane == 0)
                kb_s[T] = (d2 > d1 || (d2 == d1 && i2 < i1)) ? i2 : i1;
        }
    }
    __syncthreads();

    // codebook gather -> out (coalesced float4): 64 tokens x 32 float4
#pragma unroll
    for (int i = 0; i < 8; ++i) {
        const int f = tid + i * BLOCK;
        const int T = f >> 5, p = f & 31;
        const int kb = kb_s[T];
        float4 cv = *(const float4*)(codebook +
                     (size_t)(g * NUM_VARS + kb) * VAR_DIM + p * 4);
        *(float4*)(out + (size_t)(n0 + T) * (GROUPS * VAR_DIM) + g * VAR_DIM + p * 4) = cv;
    }

    const float scale = 1.f / (float)NTOK;
    for (int i = tid; i < NUM_VARS; i += BLOCK)
        atomicAdd(&avg_out[g * NUM_VARS + i], avg_s[i] * scale);
}

// ---------------- fallback path (no workspace): in-loop W split ------------
__global__ __launch_bounds__(BLOCK, 2)
void vq_mfma_kernel(const float* __restrict__ x,
                    const float* __restrict__ W,
                    const float* __restrict__ bias,
                    const float* __restrict__ codebook,
                    float* __restrict__ out,
                    float* __restrict__ avg_out) {
    __shared__ u16 xs_hi[TM][XP];
    __shared__ u16 xs_lo[TM][XP];
    __shared__ float avg_s[NUM_VARS];
    __shared__ float tv_s[TM][4][2];
    __shared__ int   ti_s[TM][4][2];
    __shared__ float m_s[TM], gap_s[TM], sum_s[TM];
    __shared__ int   i1_s[TM], i2_s[TM], kb_s[TM];

    const int tid  = threadIdx.x;
    const int lane = tid & 63;
    const int ty   = tid >> 6;
    const int l15  = lane & 15;
    const int l4   = lane >> 4;
    const int g    = blockIdx.x & 1;
    const int n0   = (blockIdx.x >> 1) * TM;

    for (int i = tid; i < NUM_VARS; i += BLOCK) avg_s[i] = 0.f;

    const f32x4 zf = {0.f, 0.f, 0.f, 0.f};
    f32x4 acc[2][5];
#pragma unroll
    for (int rt = 0; rt < 2; ++rt)
#pragma unroll
        for (int ct = 0; ct < 5; ++ct) acc[rt][ct] = zf;

    const int vw = g * NUM_VARS + ty * 80;

    for (int c = 0; c < DIM / KCH; ++c) {
        __syncthreads();
        {
            const int t  = tid >> 3;
            const int kb = (tid & 7) * 4;
            const float* xp = x + (size_t)(n0 + t) * DIM + c * KCH;
#pragma unroll
            for (int i = 0; i < 8; ++i) {
                const int k = kb + i * 32;
                float4 v = *(const float4*)(xp + k);
                u16x4 hv, lv; u16 h, l;
                split2(v.x, h, l); hv[0] = h; lv[0] = l;
                split2(v.y, h, l); hv[1] = h; lv[1] = l;
                split2(v.z, h, l); hv[2] = h; lv[2] = l;
                split2(v.w, h, l); hv[3] = h; lv[3] = l;
                *(u16x4*)&xs_hi[t][k] = hv;
                *(u16x4*)&xs_lo[t][k] = lv;
            }
        }
        __syncthreads();
#pragma unroll
        for (int ks = 0; ks < KCH / 32; ++ks) {
            const int ko = ks * 32 + 8 * l4;
            bf16x8 ah0 = *(const bf16x8*)&xs_hi[l15][ko];
            bf16x8 al0 = *(const bf16x8*)&xs_lo[l15][ko];
            bf16x8 ah1 = *(const bf16x8*)&xs_hi[16 + l15][ko];
            bf16x8 al1 = *(const bf16x8*)&xs_lo[16 + l15][ko];
            const int kg = c * KCH + ks * 32 + 8 * l4;
#pragma unroll
            for (int ct = 0; ct < 5; ++ct) {
                const float* wp = W + (size_t)(vw + ct * 16 + l15) * DIM + kg;
                float4 wa = *(const float4*)wp;
                float4 wb = *(const float4*)(wp + 4);
                bf16x8 bh, bl; u16 h, l;
                split2(wa.x, h, l); bh[0] = (short)h; bl[0] = (short)l;
                split2(wa.y, h, l); bh[1] = (short)h; bl[1] = (short)l;
                split2(wa.z, h, l); bh[2] = (short)h; bl[2] = (short)l;
                split2(wa.w, h, l); bh[3] = (short)h; bl[3] = (short)l;
                split2(wb.x, h, l); bh[4] = (short)h; bl[4] = (short)l;
                split2(wb.y, h, l); bh[5] = (short)h; bl[5] = (short)l;
                split2(wb.z, h, l); bh[6] = (short)h; bl[6] = (short)l;
                split2(wb.w, h, l); bh[7] = (short)h; bl[7] = (short)l;
                acc[0][ct] = __builtin_amdgcn_mfma_f32_16x16x32_bf16(ah0, bh, acc[0][ct], 0, 0, 0);
                acc[0][ct] = __builtin_amdgcn_mfma_f32_16x16x32_bf16(ah0, bl, acc[0][ct], 0, 0, 0);
                acc[0][ct] = __builtin_amdgcn_mfma_f32_16x16x32_bf16(al0, bh, acc[0][ct], 0, 0, 0);
                acc[1][ct] = __builtin_amdgcn_mfma_f32_16x16x32_bf16(ah1, bh, acc[1][ct], 0, 0, 0);
                acc[1][ct] = __builtin_amdgcn_mfma_f32_16x16x32_bf16(ah1, bl, acc[1][ct], 0, 0, 0);
                acc[1][ct] = __builtin_amdgcn_mfma_f32_16x16x32_bf16(al1, bh, acc[1][ct], 0, 0, 0);
            }
        }
    }

#pragma unroll
    for (int ct = 0; ct < 5; ++ct) {
        float bv = bias[vw + ct * 16 + l15];
#pragma unroll
        for (int rt = 0; rt < 2; ++rt)
#pragma unroll
            for (int j = 0; j < 4; ++j) acc[rt][ct][j] += bv;
    }

#pragma unroll
    for (int rt = 0; rt < 2; ++rt)
#pragma unroll
    for (int j = 0; j < 4; ++j) {
        float v1 = -3.4e38f, v2 = -3.4e38f;
        int   i1 = 0x7fffffff, i2 = 0x7fffffff;
#pragma unroll
        for (int ct = 0; ct < 5; ++ct) {
            float val = acc[rt][ct][j];
            int   vi  = ty * 80 + ct * 16 + l15;
            if ((val > v1) || (val == v1 && vi < i1)) { v2 = v1; i2 = i1; v1 = val; i1 = vi; }
            else if ((val > v2) || (val == v2 && vi < i2)) { v2 = val; i2 = vi; }
        }
#pragma unroll
        for (int off = 1; off <= 8; off <<= 1) {
            float o1 = __shfl_xor(v1, off); int oi1 = __shfl_xor(i1, off);
            float o2 = __shfl_xor(v2, off); int oi2 = __shfl_xor(i2, off);
            if ((o1 > v1) || (o1 == v1 && oi1 < i1)) { v2 = v1; i2 = i1; v1 = o1; i1 = oi1; }
            else if ((o1 > v2) || (o1 == v2 && oi1 < i2)) { v2 = o1; i2 = oi1; }
            if ((o2 > v1) || (o2 == v1 && oi2 < i1)) { v2 = v1; i2 = i1; v1 = o2; i1 = oi2; }
            else if ((o2 > v2) || (o2 == v2 && oi2 < i2)) { v2 = o2; i2 = oi2; }
        }
        if (l15 == 0) {
            const int T = rt * 16 + l4 * 4 + j;
            tv_s[T][ty][0] = v1; tv_s[T][ty][1] = v2;
            ti_s[T][ty][0] = i1; ti_s[T][ty][1] = i2;
        }
    }
    __syncthreads();

    if (tid < TM) {
        float v1 = -3.4e38f, v2 = -3.4e38f;
        int   i1 = 0x7fffffff, i2 = 0x7fffffff;
#pragma unroll
        for (int w = 0; w < 4; ++w)
#pragma unroll
            for (int q = 0; q < 2; ++q) {
                float val = tv_s[tid][w][q]; int vi = ti_s[tid][w][q];
                if ((val > v1) || (val == v1 && vi < i1)) { v2 = v1; i2 = i1; v1 = val; i1 = vi; }
                else if ((val > v2) || (val == v2 && vi < i2)) { v2 = val; i2 = vi; }
            }
        m_s[tid] = v1; gap_s[tid] = v1 - v2;
        i1_s[tid] = i1; i2_s[tid] = i2; kb_s[tid] = i1; sum_s[tid] = 0.f;
    }
    __syncthreads();

#pragma unroll
    for (int rt = 0; rt < 2; ++rt)
#pragma unroll
    for (int j = 0; j < 4; ++j) {
        const int T = rt * 16 + l4 * 4 + j;
        const float m = m_s[T];
        float s = 0.f;
#pragma unroll
        for (int ct = 0; ct < 5; ++ct) {
            float e = expf(acc[rt][ct][j] - m);
            acc[rt][ct][j] = e;
            s += e;
        }
#pragma unroll
        for (int off = 1; off <= 8; off <<= 1) s += __shfl_xor(s, off);
        if (l15 == 0) atomicAdd(&sum_s[T], s);
    }
    __syncthreads();

#pragma unroll
    for (int ct = 0; ct < 5; ++ct) {
        float tot = 0.f;
#pragma unroll
        for (int rt = 0; rt < 2; ++rt)
#pragma unroll
        for (int j = 0; j < 4; ++j) {
            const int T = rt * 16 + l4 * 4 + j;
            float v = acc[rt][ct][j] / sum_s[T];
            v += __shfl_xor(v, 16);
            v += __shfl_xor(v, 32);
            tot += v;
        }
        if (l4 == 0) avg_s[ty * 80 + ct * 16 + l15] += tot;
    }

    for (int t8 = 0; t8 < 8; ++t8) {
        const int T = ty * 8 + t8;
        if (gap_s[T] <= 0.05f) {
            const int i1 = i1_s[T], i2 = i2_s[T];
            const float* xr = x + (size_t)(n0 + T) * DIM;
            const float* w1 = W + (size_t)(g * NUM_VARS + i1) * DIM;
            const float* w2 = W + (size_t)(g * NUM_VARS + i2) * DIM;
            double d1 = 0.0, d2 = 0.0;
            for (int k = lane; k < DIM; k += 64) {
                double xv = (double)xr[k];
                d1 += xv * (double)w1[k];
                d2 += xv * (double)w2[k];
            }
#pragma unroll
            for (int off = 1; off <= 32; off <<= 1) {
                d1 += __shfl_xor(d1, off);
                d2 += __shfl_xor(d2, off);
            }
            d1 += (double)bias[g * NUM_VARS + i1];
            d2 += (double)bias[g * NUM_VARS + i2];
            if (lane == 0)
                kb_s[T] = (d2 > d1 || (d2 == d1 && i2 < i1)) ? i2 : i1;
        }
    }
    __syncthreads();

#pragma unroll
    for (int i = 0; i < 4; ++i) {
        const int f = tid + i * BLOCK;
        const int T = f >> 5, p = f & 31;
        const int kb = kb_s[T];
        float4 cv = *(const float4*)(codebook +
                     (size_t)(g * NUM_VARS + kb) * VAR_DIM + p * 4);
        *(float4*)(out + (size_t)(n0 + T) * (GROUPS * VAR_DIM) + g * VAR_DIM + p * 4) = cv;
    }

    const float scale = 1.f / (float)NTOK;
    for (int i = tid; i < NUM_VARS; i += BLOCK)
        atomicAdd(&avg_out[g * NUM_VARS + i], avg_s[i] * scale);
}

extern "C" void kernel_launch(void* const* d_in, const int* in_sizes, int n_in,
                              void* d_out, int out_size, void* d_ws, size_t ws_size,
                              hipStream_t stream) {
    const float* x  = (const float*)d_in[0];
    const float* W  = (const float*)d_in[1];
    const float* b  = (const float*)d_in[2];
    const float* cb = (const float*)d_in[3];
    float* out = (float*)d_out;
    float* avg = out + (size_t)NTOK * GROUPS * VAR_DIM;

    hipMemsetAsync(avg, 0, NVT * sizeof(float), stream);

    const size_t wpk_bytes = (size_t)NT16 * NKS * 2 * 512 * sizeof(u16);   // 1.31 MB

    if (ws_size >= wpk_bytes) {
        u16* Wpk = (u16*)d_ws;
        pack_w_kernel<<<(NT16 * NKS * 64 * 8 + 255) / 256, 256, 0, stream>>>(W, Wpk);
        vq_mfma_fused_kernel<<<(NTOK / TMF) * GROUPS, BLOCK, 0, stream>>>(
            x, W, Wpk, b, cb, out, avg);
    } else {
        vq_mfma_kernel<<<(NTOK / TM) * GROUPS, BLOCK, 0, stream>>>(x, W, b, cb, out, avg);
    }
}